// Round 5
// baseline (77.990 us; speedup 1.0000x reference)
//
#include <hip/hip_runtime.h>

// DecisionTreePolicy — complete binary tree, depth 15 (32767 nodes).
// Internal 0..16382 (children 2i+1/2i+2), leaves 16383..32766 -> exactly 14
// steps from root; out[b] = leaf_logits[leaf(b)].
//
// R1/R2: scattered obs gathers -> ~470 MB HBM re-fetch, 84us. R4: stream obs
// through LDS (coalesced, paid once), whole tree in LDS (thr f32 64KB +
// feat u8 16KB), traversal = ds_reads; 68.5us. R4 gap analysis: BLOCK=256 at
// 1 block/CU = 1 wave/SIMD -> the 14-step dependent-LDS chain (~1.4us/tile)
// and the vmcnt drain are fully exposed. R5: BLOCK=1024 (4 waves/SIMD) so
// latency hides under wave interleave; traversal redundancy (16 waves x same
// 64 rows) costs only LDS throughput, under the per-CU HBM budget.

#define N_INTERN  16383
#define N_FEAT    256
#define N_ACT     64
#define BATCH     262144
#define BLOCK     1024
#define GRID      256
#define ROWS_PB   (BATCH / GRID)          // 1024 rows per block
#define TILE_ROWS 64
#define TILES     (ROWS_PB / TILE_ROWS)   // 16
#define DEPTH     14
#define PF_N      4                       // float4 loads/thread/tile: 64KB/1024thr/16B

typedef float f32x4 __attribute__((ext_vector_type(4)));

struct __align__(16) Smem {
    f32x4         obs4[TILE_ROWS * N_FEAT / 4];  // 65536 B — one obs tile
    float         thr [N_INTERN];                // 65532 B — all internal thresholds
    unsigned char feat[N_INTERN];                // 16383 B — feature ids fit in u8
};  // ~147.4 KB of 160 KB -> 1 block/CU

__global__ __launch_bounds__(BLOCK, 1) void tree_policy_kernel(
    const float* __restrict__ obs,          // [BATCH][N_FEAT]
    const int*   __restrict__ features,     // [N_NODES]
    const float* __restrict__ thresholds,   // [N_NODES]
    const float* __restrict__ leaf_logits,  // [N_NODES][N_ACT]
    float*       __restrict__ out)          // [BATCH][N_ACT]
{
    __shared__ Smem sm;
    const int tid  = threadIdx.x;
    const int lane = tid & 63;

    // ---- pack tree into LDS (one-time, coalesced, L2-sourced) ----
    for (int i = tid; i < N_INTERN; i += BLOCK) {
        sm.thr[i]  = thresholds[i];
        sm.feat[i] = (unsigned char)features[i];
    }

    const long rowBase = (long)blockIdx.x * ROWS_PB;

    // ---- prefetch tile 0 into registers (streaming: nontemporal) ----
    f32x4 pf[PF_N];
    {
        const f32x4* src = (const f32x4*)(obs + rowBase * N_FEAT);
#pragma unroll
        for (int k = 0; k < PF_N; ++k)
            pf[k] = __builtin_nontemporal_load(&src[tid + k * BLOCK]);
    }

    for (int t = 0; t < TILES; ++t) {
        __builtin_amdgcn_sched_barrier(0);
        __builtin_amdgcn_s_barrier();            // A: all waves done reading obs[t-1]
        // regs -> LDS (compiler inserts the vmcnt wait for pf here)
#pragma unroll
        for (int k = 0; k < PF_N; ++k)
            sm.obs4[tid + k * BLOCK] = pf[k];
        // issue prefetch of tile t+1 — stays in flight across the barrier;
        // traversal below is LDS-only so no vmcnt wait touches these loads.
        if (t + 1 < TILES) {
            const f32x4* src =
                (const f32x4*)(obs + (rowBase + (long)(t + 1) * TILE_ROWS) * N_FEAT);
#pragma unroll
            for (int k = 0; k < PF_N; ++k)
                pf[k] = __builtin_nontemporal_load(&src[tid + k * BLOCK]);
        }
        asm volatile("s_waitcnt lgkmcnt(0)" ::: "memory");  // my ds_writes done
        __builtin_amdgcn_s_barrier();            // B: obs[t] (and tree, t=0) visible
        __builtin_amdgcn_sched_barrier(0);       // don't hoist ds_reads above B

        // ---- traversal: row = lane (all 16 waves redundantly compute the tile;
        //      redundancy costs LDS throughput only, buys wave-level latency hiding) ----
        const float* myrow = (const float*)sm.obs4 + lane * N_FEAT;
        int node = 0;
#pragma unroll
        for (int d = 0; d < DEPTH; ++d) {
            const float th = sm.thr[node];       // ds_read_b32
            const int   f  = sm.feat[node];      // ds_read_u8
            const float x  = myrow[f];           // ds_read_b32 within own row
            node = 2 * node + ((x <= th) ? 1 : 2);   // reference NaN semantics
        }
        // node = leaf id in [16383, 32766]

        // ---- epilogue: 1024 float4 stores cover the 64x64 tile exactly ----
        const long outRow0 = rowBase + (long)t * TILE_ROWS;
        {
            const int r     = tid >> 4;          // row in tile [0,64)
            const int chunk = tid & 15;          // float4 chunk within 64-float row
            const int leaf  = __shfl(node, r, 64);
            const f32x4 v   = *(const f32x4*)(leaf_logits + (size_t)leaf * N_ACT + chunk * 4);
            __builtin_nontemporal_store(v, (f32x4*)(out + (outRow0 + r) * N_ACT + chunk * 4));
        }
    }
}

extern "C" void kernel_launch(void* const* d_in, const int* in_sizes, int n_in,
                              void* d_out, int out_size, void* d_ws, size_t ws_size,
                              hipStream_t stream) {
    const float* obs         = (const float*)d_in[0];
    const int*   features    = (const int*)  d_in[1];
    const float* thresholds  = (const float*)d_in[2];
    // d_in[3]/d_in[4] (children) unused: tree is complete by construction.
    const float* leaf_logits = (const float*)d_in[5];
    float*       out         = (float*)d_out;

    tree_policy_kernel<<<dim3(GRID), dim3(BLOCK), 0, stream>>>(
        obs, features, thresholds, leaf_logits, out);
}